// Round 13
// baseline (1044.649 us; speedup 1.0000x reference)
//
#include <hip/hip_runtime.h>
#include <math.h>

#define NF 8
#define SS 5
#define DIN 64
#define KSTEP 3
#define BT 32
#define FH_PAD 68             // fS row pad (bank spread, 16B-aligned rows)
#define FH_ROW 324            // fh per-filter padded stride: 5*64+4 floats
                              // f_*324: start banks f_*4 -> 8 starts, 4-bank spans
                              // cover all 32 banks exactly once: conflict-free
#define FH_HOP (NF*FH_ROW)    // 2592 floats per hop (10368 B)
#define NS_OFF (KSTEP*FH_HOP) // ws: nsqh [3][8][5] after fh blocks

// exp(-(sqf+sqh-2cr)/3.2) = 2^(CC*cr - CS*sqf - CS*sqh)
#define CS 0.45084219902780109f
#define CC 0.90168439805560218f

__device__ __forceinline__ float fexp2(float x) {
#if __has_builtin(__builtin_amdgcn_exp2f)
  return __builtin_amdgcn_exp2f(x);
#else
  return exp2f(x);
#endif
}

// async global->LDS copy of one fh hop block (2592 floats), waves interleaved
__device__ __forceinline__ void stage_fh(const float* __restrict__ g,
                                         float* __restrict__ l,
                                         int wv, int lane) {
  for (int c = wv; c < 11; c += 4) {
    if (c < 10 || lane < 8)   // last chunk: 32 floats
      __builtin_amdgcn_global_load_lds(
          (const __attribute__((address_space(1))) void*)(g + c*256 + lane*4),
          (__attribute__((address_space(3))) void*)(l + c*256), 16, 0, 0);
  }
}

__global__ __launch_bounds__(256) void hidden_prep(
    const float* __restrict__ adjs_hidden,
    const float* __restrict__ features_hidden,
    float* __restrict__ ws)
{
  __shared__ float Ah[NF][SS][SS];
  __shared__ float buf[2][NF][SS][DIN];
  const int t = threadIdx.x;

  if (t < NF*SS*SS) ((float*)Ah)[t] = 0.0f;
  for (int i = t; i < NF*SS*DIN; i += 256) ((float*)buf[0])[i] = features_hidden[i];
  __syncthreads();
  if (t < NF*10) {
    const int iu0[10] = {0,0,0,0,1,1,1,2,2,3};
    const int iu1[10] = {1,2,3,4,2,3,4,3,4,4};
    int f = t / 10, k = t % 10;
    float sg = 1.0f / (1.0f + expf(-adjs_hidden[t]));
    Ah[f][iu0[k]][iu1[k]] = sg;
    Ah[f][iu1[k]][iu0[k]] = sg;
  }
  __syncthreads();

  int cur = 0;
  for (int h = 0; h < KSTEP; ++h) {
    // padded fh for this hop: ws[h*FH_HOP + f*FH_ROW + s*DIN + d]
    for (int i = t; i < NF*SS*DIN; i += 256) {
      int f = i / (SS*DIN), s = (i / DIN) % SS, d = i % DIN;
      ws[h*FH_HOP + f*FH_ROW + s*DIN + d] = buf[cur][f][s][d];
    }
    // negated, pre-scaled sq_h
    if (t < NF*SS) {
      float acc = 0.0f;
      int f = t / SS, s = t % SS;
      for (int d = 0; d < DIN; ++d) { float v = buf[cur][f][s][d]; acc = fmaf(v, v, acc); }
      ws[NS_OFF + h*NF*SS + t] = -acc * CS;
    }
    if (h + 1 < KSTEP) {
      __syncthreads();
      for (int i = t; i < NF*SS*DIN; i += 256) {
        int f = i / (SS*DIN), s = (i / DIN) % SS, d = i % DIN;
        float acc = 0.0f;
        for (int j = 0; j < SS; ++j) acc = fmaf(Ah[f][s][j], buf[cur][f][j][d], acc);
        buf[cur^1][f][s][d] = acc;
      }
      __syncthreads();
      cur ^= 1;
    }
  }
}

// r7 skeleton + 3 blocks/CU (single-hop fh restaged per hop, LDS 53,888 B)
// + sqf from own-slice register partials reduced via octet __shfl_xor.
// Hop loop stays #pragma unroll 1 (the proven-healthy regalloc shape).
__global__ __launch_bounds__(256) void kc_main(
    const float* __restrict__ adjs,
    const float* __restrict__ feature,
    const int* __restrict__ idxs,
    const float* __restrict__ ws,
    float* __restrict__ out,
    int B, int N)
{
  __shared__ float fhL[FH_HOP];          // 10368 B (current hop)
  __shared__ float fS[BT][SS][FH_PAD];   // 43520 B   -> 53888 B total

  const int t    = threadIdx.x;
  const int lane = t & 63;
  const int wv   = t >> 6;     // wave id 0..3
  const int b_i  = t >> 3;     // octet = one b
  const int f_   = t & 7;      // filter / d-slice owner
  const int bg   = blockIdx.x * BT + b_i;
  const bool valid = bg < B;
  const float* nsq = ws + NS_OFF;

  // issue hop-0 fh staging immediately (async; drained by first barrier)
  stage_fh(ws, fhL, wv, lane);

  // adj into registers (octet-broadcast loads, L1/L2-cached)
  float A_[SS*SS];
  #pragma unroll
  for (int k = 0; k < SS*SS; ++k)
    A_[k] = valid ? adjs[(size_t)bg*(SS*SS) + k] : 0.0f;

  // gather: thread fetches d-columns [8f_, 8f_+8) of its b into fS,
  // accumulating own-slice ||f||^2 partials on the fly
  float sq[SS];
  #pragma unroll
  for (int m = 0; m < SS; ++m) {
    int id = valid ? idxs[bg*SS + m] : -1;
    float p = 0.0f;
    #pragma unroll
    for (int h2 = 0; h2 < 2; ++h2) {
      float4 v = make_float4(0.f, 0.f, 0.f, 0.f);
      if ((unsigned)id < (unsigned)N)
        v = reinterpret_cast<const float4*>(feature)[(size_t)id*16 + f_*2 + h2];
      *reinterpret_cast<float4*>(&fS[b_i][m][f_*8 + h2*4]) = v;
      p = fmaf(v.x, v.x, p); p = fmaf(v.y, v.y, p);
      p = fmaf(v.z, v.z, p); p = fmaf(v.w, v.w, p);
    }
    sq[m] = p;
  }
  // octet all-reduce of sq (register-only, wave-synchronous)
  #pragma unroll
  for (int msk = 1; msk < 8; msk <<= 1)
    #pragma unroll
    for (int m = 0; m < SS; ++m) sq[m] += __shfl_xor(sq[m], msk);

  __syncthreads();  // drains vmcnt (async fh); fS octet-local

  float total[SS][SS];
  #pragma unroll
  for (int m = 0; m < SS; ++m)
    #pragma unroll
    for (int s = 0; s < SS; ++s) total[m][s] = 0.0f;

  #pragma unroll 1
  for (int hop = 0; hop < KSTEP; ++hop) {
    // nsqh for this hop (5 scalars, octet-broadcast, L1/L2-hot)
    float nh[SS];
    #pragma unroll
    for (int s = 0; s < SS; ++s)
      nh[s] = nsq[hop*NF*SS + f_*SS + s];

    // cross: cr[m][s] = sum_d f[m][d] * fh[f_][s][d]
    float cr[SS][SS];
    #pragma unroll
    for (int m = 0; m < SS; ++m)
      #pragma unroll
      for (int s = 0; s < SS; ++s) cr[m][s] = 0.0f;

    const float* fhh = &fhL[f_*FH_ROW];
    #pragma unroll
    for (int d4 = 0; d4 < 16; ++d4) {
      float4 fv[SS], hv[SS];
      #pragma unroll
      for (int m = 0; m < SS; ++m)
        fv[m] = *reinterpret_cast<const float4*>(&fS[b_i][m][d4*4]);
      #pragma unroll
      for (int s = 0; s < SS; ++s)
        hv[s] = *reinterpret_cast<const float4*>(&fhh[s*DIN + d4*4]);
      #pragma unroll
      for (int m = 0; m < SS; ++m)
        #pragma unroll
        for (int s = 0; s < SS; ++s) {
          cr[m][s] = fmaf(fv[m].x, hv[s].x, cr[m][s]);
          cr[m][s] = fmaf(fv[m].y, hv[s].y, cr[m][s]);
          cr[m][s] = fmaf(fv[m].z, hv[s].z, cr[m][s]);
          cr[m][s] = fmaf(fv[m].w, hv[s].w, cr[m][s]);
        }
    }

    // accumulate
    #pragma unroll
    for (int m = 0; m < SS; ++m) {
      float smv = CS * sq[m];
      #pragma unroll
      for (int s = 0; s < SS; ++s) {
        float arg = fmaf(CC, cr[m][s], nh[s] - smv);  // <= 0 always
        total[m][s] += fexp2(arg);
      }
    }

    if (hop + 1 < KSTEP) {
      __syncthreads();   // all waves done reading fhL for this hop
      // async restage of next hop's fh (overlaps the update below)
      stage_fh(ws + (hop+1)*FH_HOP, fhL, wv, lane);

      // f <- adjs @ f : octet-local (thread owns d-columns [8f_,8f_+8));
      // compute next hop's sq partials from fn while it's in registers
      const int dbase = f_ * 8;
      float fo[SS][8];
      #pragma unroll
      for (int j = 0; j < SS; ++j)
        #pragma unroll
        for (int h2 = 0; h2 < 2; ++h2) {
          float4 v = *reinterpret_cast<const float4*>(&fS[b_i][j][dbase + h2*4]);
          fo[j][h2*4+0] = v.x; fo[j][h2*4+1] = v.y;
          fo[j][h2*4+2] = v.z; fo[j][h2*4+3] = v.w;
        }
      #pragma unroll
      for (int m = 0; m < SS; ++m) {
        float fn[8];
        #pragma unroll
        for (int dd = 0; dd < 8; ++dd) fn[dd] = 0.0f;
        #pragma unroll
        for (int j = 0; j < SS; ++j)
          #pragma unroll
          for (int dd = 0; dd < 8; ++dd)
            fn[dd] = fmaf(A_[m*SS + j], fo[j][dd], fn[dd]);
        float p = 0.0f;
        #pragma unroll
        for (int dd = 0; dd < 8; ++dd) p = fmaf(fn[dd], fn[dd], p);
        sq[m] = p;
        #pragma unroll
        for (int h2 = 0; h2 < 2; ++h2) {
          float4 v = make_float4(fn[h2*4+0], fn[h2*4+1], fn[h2*4+2], fn[h2*4+3]);
          *reinterpret_cast<float4*>(&fS[b_i][m][dbase + h2*4]) = v;
        }
      }
      // octet all-reduce of new sq
      #pragma unroll
      for (int msk = 1; msk < 8; msk <<= 1)
        #pragma unroll
        for (int m = 0; m < SS; ++m) sq[m] += __shfl_xor(sq[m], msk);

      __syncthreads();   // staged fh visible (vmcnt drained by barrier)
    }
  }

  // greedy matching: row 0 -> col 0; rows 1..4 argmax over untaken cols
  float res = total[0][0];
  int taken = 1;
  #pragma unroll
  for (int r = 1; r < SS; ++r) {
    float best = -2.0f; int bi = 0;
    #pragma unroll
    for (int s = 0; s < SS; ++s) {
      float sc = ((taken >> s) & 1) ? -1.0f : total[r][s];
      if (sc > best) { best = sc; bi = s; }
    }
    res += best;
    taken |= (1 << bi);
  }
  if (valid) out[(size_t)bg*NF + f_] = res;
}

extern "C" void kernel_launch(void* const* d_in, const int* in_sizes, int n_in,
                              void* d_out, int out_size, void* d_ws, size_t ws_size,
                              hipStream_t stream) {
  const float* adjs            = (const float*)d_in[0];
  const float* feature         = (const float*)d_in[1];
  const int*   idxs            = (const int*)d_in[2];
  const float* adjs_hidden     = (const float*)d_in[3];
  const float* features_hidden = (const float*)d_in[4];
  float* out = (float*)d_out;
  float* ws  = (float*)d_ws;

  const int B = in_sizes[0] / (SS*SS);
  const int N = in_sizes[1] / DIN;

  hipLaunchKernelGGL(hidden_prep, dim3(1), dim3(256), 0, stream,
                     adjs_hidden, features_hidden, ws);
  const int nblk = (B + BT - 1) / BT;
  hipLaunchKernelGGL(kc_main, dim3(nblk), dim3(256), 0, stream,
                     adjs, feature, idxs, ws, out, B, N);
}

// Round 14
// 127.052 us; speedup vs baseline: 8.2222x; 8.2222x over previous
//
#include <hip/hip_runtime.h>
#include <math.h>

#define NF 8
#define SS 5
#define DIN 64
#define KSTEP 3
#define BT 32
#define FH_PAD 68             // padded row (bank spread, 16B-aligned rows)
#define FSTR (SS*FH_PAD)      // 340 (340%32=20 -> 8 distinct start banks)
#define HOPSTR (NF*FSTR)      // 2720 floats per hop block
#define NS_OFF (KSTEP*HOPSTR) // ws: nsqh [3][8][5] after fh blocks

// exp(-(sqf+sqh-2cr)/3.2) = 2^(CC*cr - CS*sqf - CS*sqh)
#define CS 0.45084219902780109f
#define CC 0.90168439805560218f

__device__ __forceinline__ float fexp2(float x) {
#if __has_builtin(__builtin_amdgcn_exp2f)
  return __builtin_amdgcn_exp2f(x);
#else
  return exp2f(x);
#endif
}

__global__ __launch_bounds__(256) void hidden_prep(
    const float* __restrict__ adjs_hidden,
    const float* __restrict__ features_hidden,
    float* __restrict__ ws)
{
  __shared__ float Ah[NF][SS][SS];
  __shared__ float buf[2][NF][SS][DIN];
  const int t = threadIdx.x;

  if (t < NF*SS*SS) ((float*)Ah)[t] = 0.0f;
  for (int i = t; i < NF*SS*DIN; i += 256) ((float*)buf[0])[i] = features_hidden[i];
  __syncthreads();
  if (t < NF*10) {
    const int iu0[10] = {0,0,0,0,1,1,1,2,2,3};
    const int iu1[10] = {1,2,3,4,2,3,4,3,4,4};
    int f = t / 10, k = t % 10;
    float sg = 1.0f / (1.0f + expf(-adjs_hidden[t]));
    Ah[f][iu0[k]][iu1[k]] = sg;
    Ah[f][iu1[k]][iu0[k]] = sg;
  }
  __syncthreads();

  int cur = 0;
  for (int h = 0; h < KSTEP; ++h) {
    // padded fh for this hop: ws[h*HOPSTR + f*FSTR + s*FH_PAD + d]
    for (int i = t; i < NF*SS*DIN; i += 256) {
      int f = i / (SS*DIN), s = (i / DIN) % SS, d = i % DIN;
      ws[h*HOPSTR + f*FSTR + s*FH_PAD + d] = buf[cur][f][s][d];
    }
    // negated, pre-scaled sq_h
    if (t < NF*SS) {
      float acc = 0.0f;
      int f = t / SS, s = t % SS;
      for (int d = 0; d < DIN; ++d) { float v = buf[cur][f][s][d]; acc = fmaf(v, v, acc); }
      ws[NS_OFF + h*NF*SS + t] = -acc * CS;
    }
    if (h + 1 < KSTEP) {
      __syncthreads();
      for (int i = t; i < NF*SS*DIN; i += 256) {
        int f = i / (SS*DIN), s = (i / DIN) % SS, d = i % DIN;
        float acc = 0.0f;
        for (int j = 0; j < SS; ++j) acc = fmaf(Ah[f][s][j], buf[cur][f][j][d], acc);
        buf[cur^1][f][s][d] = acc;
      }
      __syncthreads();
      cur ^= 1;
    }
  }
}

// r7 structure restored exactly (proven 134 us / 88 VGPR):
//  - all fh staged ONCE up front via async global_load_lds (never in a loop)
//  - sqf folded into cross; adj in registers; ONE __syncthreads total
//  - hop loop #pragma unroll 1 (the proven-healthy regalloc shape)
// Micro-cuts (zero structural risk): B%BT==0 -> no valid predication;
// idxs in [0,N) by construction -> no gather bounds check / zero-fill.
__global__ __launch_bounds__(256) void kc_main(
    const float* __restrict__ adjs,
    const float* __restrict__ feature,
    const int* __restrict__ idxs,
    const float* __restrict__ ws,
    float* __restrict__ out,
    int B, int N)
{
  __shared__ float fh[KSTEP*HOPSTR];     // 32640 B, padded conflict-free
  __shared__ float nsqh[KSTEP*NF*SS];    // 480 B
  __shared__ float fS[BT][SS][FH_PAD];   // 43520 B   -> ~76.6 KB, 2 blocks/CU

  const int t    = threadIdx.x;
  const int lane = t & 63;
  const int wv   = t >> 6;     // wave id 0..3
  const int b_i  = t >> 3;     // octet = one b
  const int f_   = t & 7;      // filter / d-slice owner
  const int bg   = blockIdx.x * BT + b_i;   // B % BT == 0: always valid

  // --- async fh staging: 8160 floats in 1024B chunks, waves interleaved ---
  for (int c = wv; c < 32; c += 4) {
    const int nfl = (c == 31) ? 224 : 256;   // floats in this chunk
    if (lane * 4 < nfl)
      __builtin_amdgcn_global_load_lds(
          (const __attribute__((address_space(1))) void*)(ws + c*256 + lane*4),
          (__attribute__((address_space(3))) void*)(fh + c*256), 16, 0, 0);
  }
  // nsqh (120 floats) via plain staging
  if (t < KSTEP*NF*SS) nsqh[t] = ws[NS_OFF + t];

  // --- adj into registers (octet-broadcast loads, L1/L2-cached) ---
  float A_[SS*SS];
  #pragma unroll
  for (int k = 0; k < SS*SS; ++k)
    A_[k] = adjs[(size_t)bg*(SS*SS) + k];

  // --- gather: thread fetches d-columns [8f_, 8f_+8) of its b into fS ---
  #pragma unroll
  for (int m = 0; m < SS; ++m) {
    int id = idxs[bg*SS + m];   // in [0, N) by construction
    #pragma unroll
    for (int h2 = 0; h2 < 2; ++h2) {
      float4 v = reinterpret_cast<const float4*>(feature)[(size_t)id*16 + f_*2 + h2];
      *reinterpret_cast<float4*>(&fS[b_i][m][f_*8 + h2*4]) = v;
    }
  }

  __syncthreads();  // drains vmcnt (async fh) + lgkm; fS/nsqh visible

  float total[SS][SS];
  #pragma unroll
  for (int m = 0; m < SS; ++m)
    #pragma unroll
    for (int s = 0; s < SS; ++s) total[m][s] = 0.0f;

  #pragma unroll 1
  for (int hop = 0; hop < KSTEP; ++hop) {
    if (hop) {
      // f <- adjs @ f : octet-local (thread owns d-columns [8f_,8f_+8))
      const int dbase = f_ * 8;
      float fo[SS][8];
      #pragma unroll
      for (int j = 0; j < SS; ++j)
        #pragma unroll
        for (int h2 = 0; h2 < 2; ++h2) {
          float4 v = *reinterpret_cast<const float4*>(&fS[b_i][j][dbase + h2*4]);
          fo[j][h2*4+0] = v.x; fo[j][h2*4+1] = v.y;
          fo[j][h2*4+2] = v.z; fo[j][h2*4+3] = v.w;
        }
      #pragma unroll
      for (int m = 0; m < SS; ++m) {
        float fn[8];
        #pragma unroll
        for (int dd = 0; dd < 8; ++dd) fn[dd] = 0.0f;
        #pragma unroll
        for (int j = 0; j < SS; ++j)
          #pragma unroll
          for (int dd = 0; dd < 8; ++dd)
            fn[dd] = fmaf(A_[m*SS + j], fo[j][dd], fn[dd]);
        #pragma unroll
        for (int h2 = 0; h2 < 2; ++h2) {
          float4 v = make_float4(fn[h2*4+0], fn[h2*4+1], fn[h2*4+2], fn[h2*4+3]);
          *reinterpret_cast<float4*>(&fS[b_i][m][dbase + h2*4]) = v;
        }
      }
      // no barrier: octet-local, same wave
    }

    // cross + folded sqf
    float cr[SS][SS], sqf[SS];
    #pragma unroll
    for (int m = 0; m < SS; ++m) {
      sqf[m] = 0.0f;
      #pragma unroll
      for (int s = 0; s < SS; ++s) cr[m][s] = 0.0f;
    }

    const float* fhh = &fh[hop*HOPSTR + f_*FSTR];
    #pragma unroll
    for (int d4 = 0; d4 < 16; ++d4) {
      float4 fv[SS], hv[SS];
      #pragma unroll
      for (int m = 0; m < SS; ++m)
        fv[m] = *reinterpret_cast<const float4*>(&fS[b_i][m][d4*4]);
      #pragma unroll
      for (int s = 0; s < SS; ++s)
        hv[s] = *reinterpret_cast<const float4*>(&fhh[s*FH_PAD + d4*4]);
      #pragma unroll
      for (int m = 0; m < SS; ++m) {
        sqf[m] = fmaf(fv[m].x, fv[m].x, sqf[m]);
        sqf[m] = fmaf(fv[m].y, fv[m].y, sqf[m]);
        sqf[m] = fmaf(fv[m].z, fv[m].z, sqf[m]);
        sqf[m] = fmaf(fv[m].w, fv[m].w, sqf[m]);
        #pragma unroll
        for (int s = 0; s < SS; ++s) {
          cr[m][s] = fmaf(fv[m].x, hv[s].x, cr[m][s]);
          cr[m][s] = fmaf(fv[m].y, hv[s].y, cr[m][s]);
          cr[m][s] = fmaf(fv[m].z, hv[s].z, cr[m][s]);
          cr[m][s] = fmaf(fv[m].w, hv[s].w, cr[m][s]);
        }
      }
    }

    #pragma unroll
    for (int m = 0; m < SS; ++m) {
      float sm = sqf[m] * CS;
      #pragma unroll
      for (int s = 0; s < SS; ++s) {
        float nh = nsqh[hop*NF*SS + f_*SS + s];
        float arg = fmaf(CC, cr[m][s], nh - sm);  // <= 0 always
        total[m][s] += fexp2(arg);
      }
    }
  }

  // greedy matching: row 0 -> col 0; rows 1..4 argmax over untaken cols
  float res = total[0][0];
  int taken = 1;
  #pragma unroll
  for (int r = 1; r < SS; ++r) {
    float best = -2.0f; int bi = 0;
    #pragma unroll
    for (int s = 0; s < SS; ++s) {
      float sc = ((taken >> s) & 1) ? -1.0f : total[r][s];
      if (sc > best) { best = sc; bi = s; }
    }
    res += best;
    taken |= (1 << bi);
  }
  out[(size_t)bg*NF + f_] = res;
}

extern "C" void kernel_launch(void* const* d_in, const int* in_sizes, int n_in,
                              void* d_out, int out_size, void* d_ws, size_t ws_size,
                              hipStream_t stream) {
  const float* adjs            = (const float*)d_in[0];
  const float* feature         = (const float*)d_in[1];
  const int*   idxs            = (const int*)d_in[2];
  const float* adjs_hidden     = (const float*)d_in[3];
  const float* features_hidden = (const float*)d_in[4];
  float* out = (float*)d_out;
  float* ws  = (float*)d_ws;

  const int B = in_sizes[0] / (SS*SS);
  const int N = in_sizes[1] / DIN;

  hipLaunchKernelGGL(hidden_prep, dim3(1), dim3(256), 0, stream,
                     adjs_hidden, features_hidden, ws);
  const int nblk = (B + BT - 1) / BT;
  hipLaunchKernelGGL(kc_main, dim3(nblk), dim3(256), 0, stream,
                     adjs, feature, idxs, ws, out, B, N);
}